// Round 6
// baseline (151.399 us; speedup 1.0000x reference)
//
#include <hip/hip_runtime.h>
#include <hip/hip_bf16.h>

// Problem constants (from reference setup_inputs)
#define T_TOK   32768
#define N_SLOTS 128
#define D_DIM   4096
#define B_DIM   4

// GEMM tiling: sums[128, 4096] = m^T[128, T] @ h[T, 4096]
#define NCHUNK  16                  // split-T
#define NSLICE  64                  // split-D
#define WCOLS   (D_DIM / NSLICE)    // 64 cols per block
#define CTOK    (T_TOK / NCHUNK)    // 2048 tokens per block
#define KB      64                  // tokens per LDS tile
#define NT      (CTOK / KB)         // 32 tiles
#define THREADS 256                 // 4 waves

typedef unsigned long long u64;
typedef __attribute__((ext_vector_type(8))) short short8;   // 8 bf16
typedef __attribute__((ext_vector_type(4))) float f32x4;

// ws layout: partial[NCHUNK][128][4096] f32 (32 MiB), counts, bitmap[T][2] u64
#define PARTIAL_BYTES ((size_t)NCHUNK * N_SLOTS * D_DIM * 4)
#define COUNTS_OFF    PARTIAL_BYTES
#define BITMAP_OFF    (PARTIAL_BYTES + 1024)

// Barrier with LDS-only drain (prefetched global loads stay in flight).
#define BAR_LGKM() do { \
    asm volatile("s_waitcnt lgkmcnt(0)" ::: "memory"); \
    __builtin_amdgcn_s_barrier(); \
  } while (0)

__device__ __forceinline__ unsigned int pack_bf2(float lo, float hi) {
  unsigned short a = __bfloat16_as_ushort(__float2bfloat16(lo));
  unsigned short b = __bfloat16_as_ushort(__float2bfloat16(hi));
  return (unsigned int)a | ((unsigned int)b << 16);
}

// ---------------------------------------------------------------------------
// Kernel 1: counts[n] (dedup semantics) + per-token 128-bit slot bitmap.
// Bitmap makes dedup free downstream: duplicate indices set the same bit.
// ---------------------------------------------------------------------------
__global__ __launch_bounds__(256) void prep_kernel(const int* __restrict__ sidx,
                                                   int* __restrict__ counts,
                                                   u64* __restrict__ bitmap) {
  __shared__ int cnt[N_SLOTS];
  const int tid = threadIdx.x;
  if (tid < N_SLOTS) cnt[tid] = 0;
  __syncthreads();

  const int t = blockIdx.x * 256 + tid;
  const int4 a = ((const int4*)sidx)[2 * t];
  const int4 b = ((const int4*)sidx)[2 * t + 1];
  int idx[8] = {a.x, a.y, a.z, a.w, b.x, b.y, b.z, b.w};

  u64 lo = 0, hi = 0;
  #pragma unroll
  for (int k = 0; k < 8; ++k) {
    int n = idx[k] & (N_SLOTS - 1);
    if (n < 64) lo |= 1ull << n; else hi |= 1ull << (n - 64);
    bool dup = false;
    #pragma unroll
    for (int j = 0; j < 8; ++j)
      if (j < k) dup |= (idx[j] == idx[k]);
    if (!dup) atomicAdd(&cnt[n], 1);
  }
  bitmap[2 * t]     = lo;
  bitmap[2 * t + 1] = hi;

  __syncthreads();
  if (tid < N_SLOTS && cnt[tid] > 0) atomicAdd(&counts[tid], cnt[tid]);
}

// ---------------------------------------------------------------------------
// Kernel 2: MFMA GEMM over the 512 MB h stream.
// A-fragments (the 0/1 mask) are built IN REGISTERS from the token bitmaps:
// no m-tile in LDS, no zero+scatter, ONE barrier per tile. LDS = 18 KiB ->
// grid 1024 gives 4 blocks/CU (16 waves/CU).
// h LDS layout (bf16): elem = col*64 + (k ^ ((col&7)<<3)), k-pairs per b32.
// mbits LDS: [half][64 tokens] u64, double-buffered.
// ---------------------------------------------------------------------------
__global__ __launch_bounds__(THREADS, 4) void sums_kernel(
    const float* __restrict__ hidden, const u64* __restrict__ bitmap,
    float* __restrict__ partial) {
  __shared__ unsigned int h_w[2][WCOLS * 32];          // 8 KiB per buffer
  __shared__ __align__(16) u64 mb_w[2][128];           // 1 KiB per buffer

  const int tid = threadIdx.x;
  const int slice = blockIdx.x & (NSLICE - 1);
  const int chunk = blockIdx.x / NSLICE;
  const int d0 = slice * WCOLS;
  const int cb = chunk * CTOK;

  // staging coords: thread owns token-pair kp (k=2kp,2kp+1) x 8 cols
  const int kp = tid & 31;
  const int cg = tid >> 5;     // col group (8 cols each)

  // compute coords
  const int lane = tid & 63;
  const int wv   = tid >> 6;   // wave 0..3 -> col-tile wv
  const int l15  = lane & 15;
  const int lk   = lane >> 4;  // k-group 0..3

  f32x4 acc[8];
  #pragma unroll
  for (int mt = 0; mt < 8; ++mt) acc[mt] = (f32x4){0.f, 0.f, 0.f, 0.f};

  float4 fa[2], fb[2];   // prefetched h: token 2kp / 2kp+1, 8 cols each
  u64 mreg = 0;          // prefetched bitmap word (threads 0..127)

  {  // prologue: loads for tile 0
    const float* hp = hidden + (size_t)(cb + 2 * kp) * D_DIM + d0 + cg * 8;
    fa[0] = ((const float4*)hp)[0];          fa[1] = ((const float4*)hp)[1];
    fb[0] = ((const float4*)(hp + D_DIM))[0]; fb[1] = ((const float4*)(hp + D_DIM))[1];
    if (tid < 128) mreg = bitmap[(size_t)cb * 2 + tid];
  }

  for (int t = 0; t < NT; ++t) {
    const int b = t & 1;

    // ---- stage h tile (transpose + f32->bf16 pack, 2-way-free b32 writes) --
    #pragma unroll
    for (int q = 0; q < 2; ++q) {
      const float ax[4] = {fa[q].x, fa[q].y, fa[q].z, fa[q].w};
      const float bx[4] = {fb[q].x, fb[q].y, fb[q].z, fb[q].w};
      #pragma unroll
      for (int c = 0; c < 4; ++c) {
        const int col = cg * 8 + q * 4 + c;
        h_w[b][col * 32 + (kp ^ ((col & 7) << 2))] = pack_bf2(ax[c], bx[c]);
      }
    }
    // ---- stage mbits: global u64 idx tb*2+tid -> [half][token] ----
    if (tid < 128) mb_w[b][((tid & 1) << 6) | (tid >> 1)] = mreg;

    // ---- issue next tile's global loads (in flight across the barrier) ----
    if (t + 1 < NT) {
      const int tb = cb + (t + 1) * KB;
      const float* hp = hidden + (size_t)(tb + 2 * kp) * D_DIM + d0 + cg * 8;
      fa[0] = ((const float4*)hp)[0];          fa[1] = ((const float4*)hp)[1];
      fb[0] = ((const float4*)(hp + D_DIM))[0]; fb[1] = ((const float4*)(hp + D_DIM))[1];
      if (tid < 128) mreg = bitmap[(size_t)tb * 2 + tid];
    }

    BAR_LGKM();   // single barrier per tile

    // ---- MFMA: acc += m^T(tile) @ h(tile), A-frags built from bitmaps ----
    const unsigned short* hb = (const unsigned short*)h_w[b];
    #pragma unroll
    for (int ks = 0; ks < 2; ++ks) {
      const int kbase = ks * 32 + lk * 8;
      const int col = wv * 16 + l15;
      const short8 bf = *(const short8*)&hb[col * 64 + (kbase ^ ((col & 7) << 3))];

      // load this lane's 8 tokens' bitmaps (broadcast across l15 -> no conflict)
      u64 w0[8], w1[8];
      #pragma unroll
      for (int g = 0; g < 4; ++g) {
        const ulonglong2 r0 = *(const ulonglong2*)&mb_w[b][kbase + 2 * g];
        w0[2 * g] = r0.x; w0[2 * g + 1] = r0.y;
        const ulonglong2 r1 = *(const ulonglong2*)&mb_w[b][64 + kbase + 2 * g];
        w1[2 * g] = r1.x; w1[2 * g + 1] = r1.y;
      }
      // pre-shift by l15 so per-mt extraction is a const-shift bfe
      unsigned int a0[8], a1[8], c0[8], c1[8];
      #pragma unroll
      for (int j = 0; j < 8; ++j) {
        const u64 s0 = w0[j] >> l15;
        a0[j] = (unsigned int)s0; a1[j] = (unsigned int)(s0 >> 32);
        const u64 s1 = w1[j] >> l15;
        c0[j] = (unsigned int)s1; c1[j] = (unsigned int)(s1 >> 32);
      }
      #pragma unroll
      for (int mt = 0; mt < 8; ++mt) {
        // bit index = row&63 = (mt&3)*16 + l15 ; half = mt>>2
        const unsigned int* src = (mt < 4) ? ((mt & 2) ? a1 : a0)
                                           : ((mt & 2) ? c1 : c0);
        const int sh = (mt & 1) * 16;
        union { unsigned int u[4]; short8 s; } cv;
        #pragma unroll
        for (int p = 0; p < 4; ++p) {
          const unsigned int b0 = (src[2 * p]     >> sh) & 1u;
          const unsigned int b1 = (src[2 * p + 1] >> sh) & 1u;
          cv.u[p] = (b0 | (b1 << 16)) * 0x3F80u;   // bf16 1.0 per set bit
        }
        acc[mt] = __builtin_amdgcn_mfma_f32_16x16x32_bf16(cv.s, bf, acc[mt], 0, 0, 0);
      }
    }
  }

  // ---- flush: plain stores, per-instr 4 rows x 16 cols x 4B = 64B segments --
  float* pbase = partial + (size_t)chunk * N_SLOTS * D_DIM;
  const int col = d0 + wv * 16 + l15;
  #pragma unroll
  for (int mt = 0; mt < 8; ++mt)
    #pragma unroll
    for (int r = 0; r < 4; ++r) {
      const int row = mt * 16 + lk * 4 + r;
      pbase[(size_t)row * D_DIM + col] = acc[mt][r];
    }
}

// ---------------------------------------------------------------------------
// Kernel 3: out = memory, with row batch_idx blended:
//   counts>0 ? 0.1*(sum_c partial[c])/counts + 0.9*cur : cur
// ---------------------------------------------------------------------------
__global__ __launch_bounds__(256) void final_kernel(const float* __restrict__ memory,
                                                    const float* __restrict__ partial,
                                                    const int* __restrict__ counts,
                                                    const int* __restrict__ bidx_p,
                                                    float* __restrict__ out) {
  const size_t i = (size_t)blockIdx.x * 256 + threadIdx.x;   // float4 index
  float4 v = ((const float4*)memory)[i];
  const size_t rowLen4 = (size_t)N_SLOTS * (D_DIM / 4);
  const size_t rowStart = (size_t)(*bidx_p) * rowLen4;
  if (i >= rowStart && i < rowStart + rowLen4) {
    const size_t rel = i - rowStart;
    const int n  = (int)(rel / (D_DIM / 4));
    const int d4 = (int)(rel % (D_DIM / 4));
    const int c = counts[n];
    if (c > 0) {
      const float4* p4 = (const float4*)partial;
      float4 s = {0.f, 0.f, 0.f, 0.f};
      #pragma unroll
      for (int ch = 0; ch < NCHUNK; ++ch) {
        float4 p = p4[((size_t)ch * N_SLOTS + n) * (D_DIM / 4) + d4];
        s.x += p.x; s.y += p.y; s.z += p.z; s.w += p.w;
      }
      const float w = 0.1f / (float)c;
      v.x = s.x * w + 0.9f * v.x;
      v.y = s.y * w + 0.9f * v.y;
      v.z = s.z * w + 0.9f * v.z;
      v.w = s.w * w + 0.9f * v.w;
    }
  }
  ((float4*)out)[i] = v;
}

extern "C" void kernel_launch(void* const* d_in, const int* in_sizes, int n_in,
                              void* d_out, int out_size, void* d_ws, size_t ws_size,
                              hipStream_t stream) {
  const float* memory = (const float*)d_in[0];
  const float* hidden = (const float*)d_in[1];
  const int*   sidx   = (const int*)d_in[2];
  const int*   bidx   = (const int*)d_in[3];
  float* out = (float*)d_out;

  char* ws = (char*)d_ws;
  float* partial = (float*)ws;
  int*   counts  = (int*)(ws + COUNTS_OFF);
  u64*   bitmap  = (u64*)(ws + BITMAP_OFF);

  // zero counts only (partial & bitmap fully overwritten every call)
  hipMemsetAsync(counts, 0, 512, stream);

  prep_kernel<<<T_TOK / 256, 256, 0, stream>>>(sidx, counts, bitmap);

  sums_kernel<<<NCHUNK * NSLICE, THREADS, 0, stream>>>(hidden, bitmap, partial);

  const int totalVec4 = B_DIM * N_SLOTS * (D_DIM / 4);   // 524288
  final_kernel<<<totalVec4 / 256, 256, 0, stream>>>(memory, partial, counts, bidx, out);
}